// Round 5
// baseline (605.326 us; speedup 1.0000x reference)
//
#include <hip/hip_runtime.h>

#define NN 100000
#define NE 1600000
#define PSHIFT 9
#define PSZ 512
#define NP ((NN + PSZ - 1) / PSZ)             // 196
#define BCHUNK 8192
#define NBIN ((NE + BCHUNK - 1) / BCHUNK)     // 196
#define SRCMASK 0x1FFFF                       // 17 bits (NN < 131072)

typedef __attribute__((ext_vector_type(8))) short short8;
typedef __attribute__((ext_vector_type(4))) float f32x4;

__device__ __forceinline__ ushort f2bf(float f) {
    uint u = __float_as_uint(f);
    return (ushort)((u + 0x7FFFu + ((u >> 16) & 1u)) >> 16);   // RNE
}
__device__ __forceinline__ float bflo(uint u) { return __uint_as_float(u << 16); }
__device__ __forceinline__ float bfhi(uint u) { return __uint_as_float(u & 0xffff0000u); }
__device__ __forceinline__ uint packbf(float a, float b) {
    return (uint)f2bf(a) | ((uint)f2bf(b) << 16);
}

// ---------------------------------------------------------------------------
// CSR build, partition-local for write locality (unchanged from round 4).
// ---------------------------------------------------------------------------
__global__ __launch_bounds__(256) void k_phist(const int* __restrict__ dst,
                                               int* __restrict__ pcnt)
{
    __shared__ int cnt[256];
    const int tid = threadIdx.x;
    cnt[tid] = 0;
    __syncthreads();
    const long e0 = (long)blockIdx.x * BCHUNK;
    for (int i = tid; i < BCHUNK; i += 256) {
        long e = e0 + i;
        if (e < NE) atomicAdd(&cnt[dst[e] >> PSHIFT], 1);
    }
    __syncthreads();
    if (cnt[tid] > 0) atomicAdd(&pcnt[tid], cnt[tid]);
}

__global__ __launch_bounds__(256) void k_pscan(const int* __restrict__ pcnt,
                                               int* __restrict__ poff,
                                               int* __restrict__ gcur,
                                               int* __restrict__ rowptr)
{
    __shared__ int tmp[256];
    const int tid = threadIdx.x;
    int v = (tid < NP) ? pcnt[tid] : 0;
    tmp[tid] = v;
    __syncthreads();
    for (int off = 1; off < 256; off <<= 1) {
        int t = (tid >= off) ? tmp[tid - off] : 0;
        __syncthreads();
        tmp[tid] += t;
        __syncthreads();
    }
    int ex = tmp[tid] - v;
    if (tid < NP) { poff[tid] = ex; gcur[tid] = ex; }
    if (tid == 0) { poff[NP] = NE; rowptr[NN] = NE; }
}

__global__ __launch_bounds__(256) void k_binning(const int* __restrict__ src,
                                                 const int* __restrict__ dst,
                                                 int* __restrict__ gcur,
                                                 uint* __restrict__ packed)
{
    __shared__ int cnt[256];
    __shared__ int base[256];
    const int tid = threadIdx.x;
    const long e0 = (long)blockIdx.x * BCHUNK;
    cnt[tid] = 0;
    __syncthreads();
    for (int i = tid; i < BCHUNK; i += 256) {
        long e = e0 + i;
        if (e < NE) atomicAdd(&cnt[dst[e] >> PSHIFT], 1);
    }
    __syncthreads();
    if (cnt[tid] > 0) base[tid] = atomicAdd(&gcur[tid], cnt[tid]);
    cnt[tid] = 0;
    __syncthreads();
    for (int i = tid; i < BCHUNK; i += 256) {
        long e = e0 + i;
        if (e < NE) {
            int d = dst[e], s = src[e];
            int p = d >> PSHIFT;
            int ofs = atomicAdd(&cnt[p], 1);
            packed[base[p] + ofs] = (uint)s | ((uint)(d & (PSZ - 1)) << 17);
        }
    }
}

__global__ __launch_bounds__(256) void k_pfill(const uint* __restrict__ packed,
                                               const int* __restrict__ poff,
                                               int* __restrict__ rowptr,
                                               int* __restrict__ col)
{
    __shared__ int cnt[PSZ];
    __shared__ int cur[PSZ];
    __shared__ int tot[256];
    const int p   = blockIdx.x;
    const int tid = threadIdx.x;
    const int beg = poff[p], end = poff[p + 1];
    cnt[tid] = 0; cnt[tid + 256] = 0;
    __syncthreads();
    for (int i = beg + tid; i < end; i += 256)
        atomicAdd(&cnt[packed[i] >> 17], 1);
    __syncthreads();
    int v0 = cnt[tid * 2], v1 = cnt[tid * 2 + 1];
    int s  = v0 + v1;
    tot[tid] = s;
    __syncthreads();
    for (int off = 1; off < 256; off <<= 1) {
        int t = (tid >= off) ? tot[tid - off] : 0;
        __syncthreads();
        tot[tid] += t;
        __syncthreads();
    }
    int ex = tot[tid] - s + beg;
    cur[tid * 2]     = ex;
    cur[tid * 2 + 1] = ex + v0;
    int n0 = p * PSZ;
    if (n0 + tid * 2     < NN) rowptr[n0 + tid * 2]     = ex;
    if (n0 + tid * 2 + 1 < NN) rowptr[n0 + tid * 2 + 1] = ex + v0;
    __syncthreads();
    for (int i = beg + tid; i < end; i += 256) {
        uint v = packed[i];
        int pos = atomicAdd(&cur[v >> 17], 1);
        col[pos] = (int)(v & SRCMASK);
    }
}

// ---------------------------------------------------------------------------
// Weight prep: WbT1[256][128] = [W1_l | W1_r]^T bf16; WbT2[128][128]
// ---------------------------------------------------------------------------
__global__ __launch_bounds__(256) void k_castw(const float* __restrict__ W1l,
                                               const float* __restrict__ W1r,
                                               const float* __restrict__ W2l,
                                               const float* __restrict__ W2r,
                                               ushort* __restrict__ WbT1,
                                               ushort* __restrict__ WbT2)
{
    int i = blockIdx.x * 256 + threadIdx.x;
    if (i < 256 * 128) {
        int c = i >> 7, k = i & 127;
        float v = (c < 128) ? W1l[k * 128 + c] : W1r[k * 128 + (c - 128)];
        WbT1[i] = f2bf(v);
    } else if (i < 256 * 128 + 128 * 128) {
        int j = i - 256 * 128;
        int c = j >> 7, k = j & 127;
        float v = (c < 64) ? W2l[k * 64 + c] : W2r[k * 64 + (c - 64)];
        WbT2[j] = f2bf(v);
    }
}

// ---------------------------------------------------------------------------
// Fused dual-GEMM per layer: [z | y] = A @ [Wl | Wr] (+bias on y part).
// A-tile (64 rows, K=128) staged once in swizzled LDS; B read from global
// (L2-resident). 4 waves; wave w covers cols [w*16*CB, (w+1)*16*CB).
// L1: A=x fp32, 256 cols -> z1s (sliced 16) bf16, y1b row-major bf16.
// L2: A=hb bf16, 128 cols -> z2s (sliced 8) bf16, y2f row-major fp32.
// ---------------------------------------------------------------------------
template <bool IS_L1>
__global__ __launch_bounds__(256) void k_gemmf(const void* __restrict__ Ap,
                                               const ushort* __restrict__ Bt,
                                               const float* __restrict__ bias,
                                               ushort* __restrict__ zs,
                                               void* __restrict__ yout)
{
    constexpr int CB = IS_L1 ? 4 : 2;          // 64-col blocks total
    __shared__ ushort As[64 * 128];

    const int tid = threadIdx.x, bm = blockIdx.x;

    for (int c = tid; c < 1024; c += 256) {
        int row  = c >> 4;
        int coff = (c & 15) * 8;
        int gr   = bm * 64 + row;
        short8 va;
        if (gr < NN) {
            if (IS_L1) {
                const float* A = (const float*)Ap;
                float4 f0 = *reinterpret_cast<const float4*>(A + (size_t)gr * 128 + coff);
                float4 f1 = *reinterpret_cast<const float4*>(A + (size_t)gr * 128 + coff + 4);
                va[0] = (short)f2bf(f0.x); va[1] = (short)f2bf(f0.y);
                va[2] = (short)f2bf(f0.z); va[3] = (short)f2bf(f0.w);
                va[4] = (short)f2bf(f1.x); va[5] = (short)f2bf(f1.y);
                va[6] = (short)f2bf(f1.z); va[7] = (short)f2bf(f1.w);
            } else {
                const ushort* A = (const ushort*)Ap;
                va = *reinterpret_cast<const short8*>(A + (size_t)gr * 128 + coff);
            }
        } else {
            va = short8{0, 0, 0, 0, 0, 0, 0, 0};
        }
        int byte = row * 256 + coff * 2;
        byte ^= ((row & 7) << 4);
        *reinterpret_cast<short8*>(reinterpret_cast<char*>(As) + byte) = va;
    }
    __syncthreads();

    const int wid = tid >> 6, lane = tid & 63;
    const int lr  = lane & 15;
    const int lk  = (lane >> 4) << 3;

    f32x4 acc[4][CB];
#pragma unroll
    for (int mi = 0; mi < 4; ++mi)
#pragma unroll
        for (int nf = 0; nf < CB; ++nf) acc[mi][nf] = f32x4{0.f, 0.f, 0.f, 0.f};

    const char* pA = reinterpret_cast<const char*>(As);

#pragma unroll
    for (int ks = 0; ks < 4; ++ks) {
        int k2 = (ks * 32 + lk) * 2;
        short8 a[4], b[CB];
#pragma unroll
        for (int mi = 0; mi < 4; ++mi) {
            int r = mi * 16 + lr;
            int byte = r * 256 + k2;
            byte ^= ((r & 7) << 4);
            a[mi] = *reinterpret_cast<const short8*>(pA + byte);
        }
#pragma unroll
        for (int nf = 0; nf < CB; ++nf) {
            int colB = wid * (16 * CB) + nf * 16 + lr;
            b[nf] = *reinterpret_cast<const short8*>(Bt + (size_t)colB * 128 + ks * 32 + lk);
        }
#pragma unroll
        for (int mi = 0; mi < 4; ++mi)
#pragma unroll
            for (int nf = 0; nf < CB; ++nf)
                acc[mi][nf] = __builtin_amdgcn_mfma_f32_16x16x32_bf16(a[mi], b[nf], acc[mi][nf], 0, 0, 0);
    }

    // D mapping: col = lane&15, row = 4*(lane>>4) + reg
#pragma unroll
    for (int mi = 0; mi < 4; ++mi) {
#pragma unroll
        for (int nf = 0; nf < CB; ++nf) {
            int colg = wid * (16 * CB) + nf * 16 + lr;
#pragma unroll
            for (int rr = 0; rr < 4; ++rr) {
                int rowg = bm * 64 + mi * 16 + ((lane >> 4) << 2) + rr;
                if (rowg < NN) {
                    float v = acc[mi][nf][rr];
                    if (IS_L1) {
                        if (colg < 128) {
                            int fg = colg >> 4, el = colg & 15;
                            zs[((size_t)fg * NN + rowg) * 16 + el] = f2bf(v);
                        } else {
                            int c2 = colg - 128;
                            ((ushort*)yout)[(size_t)rowg * 128 + c2] = f2bf(v + bias[c2]);
                        }
                    } else {
                        if (colg < 64) {
                            int fg = colg >> 3, el = colg & 7;
                            zs[((size_t)fg * NN + rowg) * 8 + el] = f2bf(v);
                        } else {
                            int c2 = colg - 64;
                            ((float*)yout)[(size_t)rowg * 64 + c2] = v + bias[c2];
                        }
                    }
                }
            }
        }
    }
}

// ---------------------------------------------------------------------------
// Gather 1 (XCD-affine): fg = bid%8 pins a 3.2MB z1 slice per XCD's L2.
// One wave per (node, fg); 8 edge-slots x 32B slice; shfl_xor reduce.
// h written row-major bf16.
// ---------------------------------------------------------------------------
__global__ __launch_bounds__(256) void k_gather1(const ushort* __restrict__ z1s,
                                                 const ushort* __restrict__ y1b,
                                                 const int* __restrict__ rowptr,
                                                 const int* __restrict__ col,
                                                 ushort* __restrict__ hb)
{
    const int fg    = blockIdx.x & 7;
    const int chunk = blockIdx.x >> 3;
    const int wid = threadIdx.x >> 6, lane = threadIdx.x & 63;
    const int n = chunk * 4 + wid;
    if (n >= NN) return;
    const int off = lane & 7, es = lane >> 3;
    const int beg = rowptr[n], end = rowptr[n + 1];
    const uint* zu = (const uint*)z1s + (size_t)fg * NN * 8;
    float a0 = 0.f, a1 = 0.f;
    for (int e = beg + es; e < end; e += 8) {
        int s = col[e];
        uint u = zu[(size_t)s * 8 + off];
        a0 += bflo(u); a1 += bfhi(u);
    }
    a0 += __shfl_xor(a0, 8);  a1 += __shfl_xor(a1, 8);
    a0 += __shfl_xor(a0, 16); a1 += __shfl_xor(a1, 16);
    a0 += __shfl_xor(a0, 32); a1 += __shfl_xor(a1, 32);
    if (es == 0) {
        float inv = 1.0f / (float)max(end - beg, 1);
        uint uy = ((const uint*)y1b)[(size_t)n * 64 + fg * 8 + off];
        float h0 = fmaxf(a0 * inv + bflo(uy), 0.f);
        float h1 = fmaxf(a1 * inv + bfhi(uy), 0.f);
        ((uint*)hb)[(size_t)n * 64 + fg * 8 + off] = packbf(h0, h1);
    }
}

// ---------------------------------------------------------------------------
// Gather 2 (XCD-affine): 8 slices of 8 cols (1.6MB each). 16 edge-slots x 16B.
// out fp32 row-major.
// ---------------------------------------------------------------------------
__global__ __launch_bounds__(256) void k_gather2(const ushort* __restrict__ z2s,
                                                 const float* __restrict__ y2f,
                                                 const int* __restrict__ rowptr,
                                                 const int* __restrict__ col,
                                                 float* __restrict__ out)
{
    const int fg    = blockIdx.x & 7;
    const int chunk = blockIdx.x >> 3;
    const int wid = threadIdx.x >> 6, lane = threadIdx.x & 63;
    const int n = chunk * 4 + wid;
    if (n >= NN) return;
    const int off = lane & 3, es = lane >> 2;
    const int beg = rowptr[n], end = rowptr[n + 1];
    const uint* zu = (const uint*)z2s + (size_t)fg * NN * 4;
    float a0 = 0.f, a1 = 0.f;
    for (int e = beg + es; e < end; e += 16) {
        int s = col[e];
        uint u = zu[(size_t)s * 4 + off];
        a0 += bflo(u); a1 += bfhi(u);
    }
    a0 += __shfl_xor(a0, 4);  a1 += __shfl_xor(a1, 4);
    a0 += __shfl_xor(a0, 8);  a1 += __shfl_xor(a1, 8);
    a0 += __shfl_xor(a0, 16); a1 += __shfl_xor(a1, 16);
    a0 += __shfl_xor(a0, 32); a1 += __shfl_xor(a1, 32);
    if (es == 0) {
        float inv = 1.0f / (float)max(end - beg, 1);
        float2 y = ((const float2*)y2f)[(size_t)n * 32 + fg * 4 + off];
        float2 o;
        o.x = a0 * inv + y.x;
        o.y = a1 * inv + y.y;
        ((float2*)out)[(size_t)n * 32 + fg * 4 + off] = o;
    }
}

extern "C" void kernel_launch(void* const* d_in, const int* in_sizes, int n_in,
                              void* d_out, int out_size, void* d_ws, size_t ws_size,
                              hipStream_t stream)
{
    const float* x   = (const float*)d_in[0];
    const int*   ei  = (const int*)d_in[1];
    const float* W1l = (const float*)d_in[2];
    const float* W1r = (const float*)d_in[3];
    const float* b1  = (const float*)d_in[4];
    const float* W2l = (const float*)d_in[5];
    const float* W2r = (const float*)d_in[6];
    const float* b2  = (const float*)d_in[7];
    float* out = (float*)d_out;

    const int* src = ei;
    const int* dst = ei + NE;

    // workspace layout
    int*  rowptr = (int*)d_ws;                      // NN+1
    int*  pcnt   = rowptr + NN + 1;                 // 256
    int*  poff   = pcnt + 256;                      // 256 (NP+1 used)
    int*  gcur   = poff + 256;                      // 256
    uint* packed = (uint*)(gcur + 256);             // NE
    int*  colA   = (int*)(packed + NE);             // NE
    uintptr_t p = (uintptr_t)(colA + NE);
    p = (p + 255) & ~(uintptr_t)255;
    ushort* WbT1 = (ushort*)p;  p += (size_t)256 * 128 * 2;
    ushort* WbT2 = (ushort*)p;  p += (size_t)128 * 128 * 2;
    p = (p + 255) & ~(uintptr_t)255;
    ushort* z1s = (ushort*)p;   p += (size_t)NN * 128 * 2;  // sliced [8][NN][16]
    ushort* y1b = (ushort*)p;   p += (size_t)NN * 128 * 2;  // row-major
    ushort* hb  = (ushort*)p;   p += (size_t)NN * 128 * 2;  // row-major
    ushort* z2s = z1s;                              // sliced [8][NN][8], alias
    float*  y2f = (float*)y1b;                      // row-major fp32, alias

    // ---- CSR build (partition-local) ----
    hipMemsetAsync(pcnt, 0, 256 * sizeof(int), stream);
    k_phist<<<NBIN, 256, 0, stream>>>(dst, pcnt);
    k_pscan<<<1, 256, 0, stream>>>(pcnt, poff, gcur, rowptr);
    k_binning<<<NBIN, 256, 0, stream>>>(src, dst, gcur, packed);
    k_pfill<<<NP, 256, 0, stream>>>(packed, poff, rowptr, colA);

    // ---- weights to bf16 (transposed) ----
    k_castw<<<(256 * 128 + 128 * 128 + 255) / 256, 256, 0, stream>>>(
        W1l, W1r, W2l, W2r, WbT1, WbT2);

    const int GM = (NN + 63) / 64;                  // 1563
    const int GG = ((NN + 3) / 4) * 8;              // 200000

    // ---- layer 1 ----
    k_gemmf<true><<<GM, 256, 0, stream>>>(x, WbT1, b1, z1s, y1b);
    k_gather1<<<GG, 256, 0, stream>>>(z1s, y1b, rowptr, colA, hb);

    // ---- layer 2 ----
    k_gemmf<false><<<GM, 256, 0, stream>>>(hb, WbT2, b2, z2s, y2f);
    k_gather2<<<GG, 256, 0, stream>>>(z2s, y2f, rowptr, colA, out);
}

// Round 6
// 280.882 us; speedup vs baseline: 2.1551x; 2.1551x over previous
//
#include <hip/hip_runtime.h>

#define NN 100000
#define NE 1600000
#define PSHIFT 9
#define PSZ 512
#define NP ((NN + PSZ - 1) / PSZ)             // 196
#define BCHUNK 8192
#define NBIN ((NE + BCHUNK - 1) / BCHUNK)     // 196
#define SRCMASK 0x1FFFF                       // 17 bits (NN < 131072)

typedef __attribute__((ext_vector_type(8))) short short8;
typedef __attribute__((ext_vector_type(4))) float f32x4;

__device__ __forceinline__ ushort f2bf(float f) {
    uint u = __float_as_uint(f);
    return (ushort)((u + 0x7FFFu + ((u >> 16) & 1u)) >> 16);   // RNE
}
__device__ __forceinline__ float bflo(uint u) { return __uint_as_float(u << 16); }
__device__ __forceinline__ float bfhi(uint u) { return __uint_as_float(u & 0xffff0000u); }
__device__ __forceinline__ uint packbf(float a, float b) {
    return (uint)f2bf(a) | ((uint)f2bf(b) << 16);
}

// ---------------------------------------------------------------------------
// CSR build, partition-local for write locality (round-4 proven).
// ---------------------------------------------------------------------------
__global__ __launch_bounds__(256) void k_phist(const int* __restrict__ dst,
                                               int* __restrict__ pcnt)
{
    __shared__ int cnt[256];
    const int tid = threadIdx.x;
    cnt[tid] = 0;
    __syncthreads();
    const long e0 = (long)blockIdx.x * BCHUNK;
    for (int i = tid; i < BCHUNK; i += 256) {
        long e = e0 + i;
        if (e < NE) atomicAdd(&cnt[dst[e] >> PSHIFT], 1);
    }
    __syncthreads();
    if (cnt[tid] > 0) atomicAdd(&pcnt[tid], cnt[tid]);
}

__global__ __launch_bounds__(256) void k_pscan(const int* __restrict__ pcnt,
                                               int* __restrict__ poff,
                                               int* __restrict__ gcur,
                                               int* __restrict__ rowptr)
{
    __shared__ int tmp[256];
    const int tid = threadIdx.x;
    int v = (tid < NP) ? pcnt[tid] : 0;
    tmp[tid] = v;
    __syncthreads();
    for (int off = 1; off < 256; off <<= 1) {
        int t = (tid >= off) ? tmp[tid - off] : 0;
        __syncthreads();
        tmp[tid] += t;
        __syncthreads();
    }
    int ex = tmp[tid] - v;
    if (tid < NP) { poff[tid] = ex; gcur[tid] = ex; }
    if (tid == 0) { poff[NP] = NE; rowptr[NN] = NE; }
}

__global__ __launch_bounds__(256) void k_binning(const int* __restrict__ src,
                                                 const int* __restrict__ dst,
                                                 int* __restrict__ gcur,
                                                 uint* __restrict__ packed)
{
    __shared__ int cnt[256];
    __shared__ int base[256];
    const int tid = threadIdx.x;
    const long e0 = (long)blockIdx.x * BCHUNK;
    cnt[tid] = 0;
    __syncthreads();
    for (int i = tid; i < BCHUNK; i += 256) {
        long e = e0 + i;
        if (e < NE) atomicAdd(&cnt[dst[e] >> PSHIFT], 1);
    }
    __syncthreads();
    if (cnt[tid] > 0) base[tid] = atomicAdd(&gcur[tid], cnt[tid]);
    cnt[tid] = 0;
    __syncthreads();
    for (int i = tid; i < BCHUNK; i += 256) {
        long e = e0 + i;
        if (e < NE) {
            int d = dst[e], s = src[e];
            int p = d >> PSHIFT;
            int ofs = atomicAdd(&cnt[p], 1);
            packed[base[p] + ofs] = (uint)s | ((uint)(d & (PSZ - 1)) << 17);
        }
    }
}

__global__ __launch_bounds__(256) void k_pfill(const uint* __restrict__ packed,
                                               const int* __restrict__ poff,
                                               int* __restrict__ rowptr,
                                               int* __restrict__ col)
{
    __shared__ int cnt[PSZ];
    __shared__ int cur[PSZ];
    __shared__ int tot[256];
    const int p   = blockIdx.x;
    const int tid = threadIdx.x;
    const int beg = poff[p], end = poff[p + 1];
    cnt[tid] = 0; cnt[tid + 256] = 0;
    __syncthreads();
    for (int i = beg + tid; i < end; i += 256)
        atomicAdd(&cnt[packed[i] >> 17], 1);
    __syncthreads();
    int v0 = cnt[tid * 2], v1 = cnt[tid * 2 + 1];
    int s  = v0 + v1;
    tot[tid] = s;
    __syncthreads();
    for (int off = 1; off < 256; off <<= 1) {
        int t = (tid >= off) ? tot[tid - off] : 0;
        __syncthreads();
        tot[tid] += t;
        __syncthreads();
    }
    int ex = tot[tid] - s + beg;
    cur[tid * 2]     = ex;
    cur[tid * 2 + 1] = ex + v0;
    int n0 = p * PSZ;
    if (n0 + tid * 2     < NN) rowptr[n0 + tid * 2]     = ex;
    if (n0 + tid * 2 + 1 < NN) rowptr[n0 + tid * 2 + 1] = ex + v0;
    __syncthreads();
    for (int i = beg + tid; i < end; i += 256) {
        uint v = packed[i];
        int pos = atomicAdd(&cur[v >> 17], 1);
        col[pos] = (int)(v & SRCMASK);
    }
}

// ---------------------------------------------------------------------------
// Weight prep: WbT1[256][128] = [W1_l | W1_r]^T bf16; WbT2[128][128]
// ---------------------------------------------------------------------------
__global__ __launch_bounds__(256) void k_castw(const float* __restrict__ W1l,
                                               const float* __restrict__ W1r,
                                               const float* __restrict__ W2l,
                                               const float* __restrict__ W2r,
                                               ushort* __restrict__ WbT1,
                                               ushort* __restrict__ WbT2)
{
    int i = blockIdx.x * 256 + threadIdx.x;
    if (i < 256 * 128) {
        int c = i >> 7, k = i & 127;
        float v = (c < 128) ? W1l[k * 128 + c] : W1r[k * 128 + (c - 128)];
        WbT1[i] = f2bf(v);
    } else if (i < 256 * 128 + 128 * 128) {
        int j = i - 256 * 128;
        int c = j >> 7, k = j & 127;
        float v = (c < 64) ? W2l[k * 64 + c] : W2r[k * 64 + (c - 64)];
        WbT2[j] = f2bf(v);
    }
}

// ---------------------------------------------------------------------------
// Fused dual-GEMM per layer: [z | y] = A @ [Wl | Wr] (+bias on y part).
// A-tile (64 rows, K=128) staged ONCE in swizzled LDS; B read from global
// (L2-resident). 4 waves; wave w covers cols [w*16*CB, (w+1)*16*CB).
// Outputs row-major: z bf16, y bf16 (L1) / fp32 (L2).
// ---------------------------------------------------------------------------
template <bool IS_L1>
__global__ __launch_bounds__(256) void k_gemmf(const void* __restrict__ Ap,
                                               const ushort* __restrict__ Bt,
                                               const float* __restrict__ bias,
                                               ushort* __restrict__ zb,
                                               void* __restrict__ yout)
{
    constexpr int CB = IS_L1 ? 4 : 2;          // 16-col fragments per wave
    constexpr int ZW = IS_L1 ? 128 : 64;       // z width
    __shared__ ushort As[64 * 128];

    const int tid = threadIdx.x, bm = blockIdx.x;

    for (int c = tid; c < 1024; c += 256) {
        int row  = c >> 4;
        int coff = (c & 15) * 8;
        int gr   = bm * 64 + row;
        short8 va;
        if (gr < NN) {
            if (IS_L1) {
                const float* A = (const float*)Ap;
                float4 f0 = *reinterpret_cast<const float4*>(A + (size_t)gr * 128 + coff);
                float4 f1 = *reinterpret_cast<const float4*>(A + (size_t)gr * 128 + coff + 4);
                va[0] = (short)f2bf(f0.x); va[1] = (short)f2bf(f0.y);
                va[2] = (short)f2bf(f0.z); va[3] = (short)f2bf(f0.w);
                va[4] = (short)f2bf(f1.x); va[5] = (short)f2bf(f1.y);
                va[6] = (short)f2bf(f1.z); va[7] = (short)f2bf(f1.w);
            } else {
                const ushort* A = (const ushort*)Ap;
                va = *reinterpret_cast<const short8*>(A + (size_t)gr * 128 + coff);
            }
        } else {
            va = short8{0, 0, 0, 0, 0, 0, 0, 0};
        }
        int byte = row * 256 + coff * 2;
        byte ^= ((row & 7) << 4);
        *reinterpret_cast<short8*>(reinterpret_cast<char*>(As) + byte) = va;
    }
    __syncthreads();

    const int wid = tid >> 6, lane = tid & 63;
    const int lr  = lane & 15;
    const int lk  = (lane >> 4) << 3;

    f32x4 acc[4][CB];
#pragma unroll
    for (int mi = 0; mi < 4; ++mi)
#pragma unroll
        for (int nf = 0; nf < CB; ++nf) acc[mi][nf] = f32x4{0.f, 0.f, 0.f, 0.f};

    const char* pA = reinterpret_cast<const char*>(As);

#pragma unroll
    for (int ks = 0; ks < 4; ++ks) {
        int k2 = (ks * 32 + lk) * 2;
        short8 a[4], b[CB];
#pragma unroll
        for (int mi = 0; mi < 4; ++mi) {
            int r = mi * 16 + lr;
            int byte = r * 256 + k2;
            byte ^= ((r & 7) << 4);
            a[mi] = *reinterpret_cast<const short8*>(pA + byte);
        }
#pragma unroll
        for (int nf = 0; nf < CB; ++nf) {
            int colB = wid * (16 * CB) + nf * 16 + lr;
            b[nf] = *reinterpret_cast<const short8*>(Bt + (size_t)colB * 128 + ks * 32 + lk);
        }
#pragma unroll
        for (int mi = 0; mi < 4; ++mi)
#pragma unroll
            for (int nf = 0; nf < CB; ++nf)
                acc[mi][nf] = __builtin_amdgcn_mfma_f32_16x16x32_bf16(a[mi], b[nf], acc[mi][nf], 0, 0, 0);
    }

    // D mapping: col = lane&15, row = 4*(lane>>4) + reg
#pragma unroll
    for (int mi = 0; mi < 4; ++mi) {
#pragma unroll
        for (int nf = 0; nf < CB; ++nf) {
            int colg = wid * (16 * CB) + nf * 16 + lr;
#pragma unroll
            for (int rr = 0; rr < 4; ++rr) {
                int rowg = bm * 64 + mi * 16 + ((lane >> 4) << 2) + rr;
                if (rowg < NN) {
                    float v = acc[mi][nf][rr];
                    if (colg < ZW) {
                        zb[(size_t)rowg * ZW + colg] = f2bf(v);
                    } else {
                        int c2 = colg - ZW;
                        if (IS_L1) ((ushort*)yout)[(size_t)rowg * 128 + c2] = f2bf(v + bias[c2]);
                        else       ((float*)yout)[(size_t)rowg * 64 + c2]  = v + bias[c2];
                    }
                }
            }
        }
    }
}

// ---------------------------------------------------------------------------
// Gather 1: hb[n] = relu( mean z1b[nbrs] + y1b[n] )  (128-wide bf16)
// One 64-lane wave per node, full 256B row per edge, 4-edge unroll for MLP.
// ---------------------------------------------------------------------------
__global__ __launch_bounds__(256) void k_gather1(const ushort* __restrict__ z1b,
                                                 const ushort* __restrict__ y1b,
                                                 const int* __restrict__ rowptr,
                                                 const int* __restrict__ col,
                                                 ushort* __restrict__ hb)
{
    const int w = threadIdx.x >> 6, lane = threadIdx.x & 63;
    const int n = blockIdx.x * 4 + w;
    if (n >= NN) return;
    const int beg = rowptr[n], end = rowptr[n + 1];
    const uint* zu = (const uint*)z1b;
    float a0 = 0.f, a1 = 0.f;
    int e = beg;
    for (; e + 3 < end; e += 4) {
        int s0 = col[e], s1 = col[e + 1], s2 = col[e + 2], s3 = col[e + 3];
        uint u0 = zu[(size_t)s0 * 64 + lane];
        uint u1 = zu[(size_t)s1 * 64 + lane];
        uint u2 = zu[(size_t)s2 * 64 + lane];
        uint u3 = zu[(size_t)s3 * 64 + lane];
        a0 += bflo(u0) + bflo(u1) + bflo(u2) + bflo(u3);
        a1 += bfhi(u0) + bfhi(u1) + bfhi(u2) + bfhi(u3);
    }
    for (; e < end; ++e) {
        uint u0 = zu[(size_t)col[e] * 64 + lane];
        a0 += bflo(u0);
        a1 += bfhi(u0);
    }
    float inv = 1.0f / (float)max(end - beg, 1);
    uint uy = ((const uint*)y1b)[(size_t)n * 64 + lane];
    float h0 = fmaxf(a0 * inv + bflo(uy), 0.f);
    float h1 = fmaxf(a1 * inv + bfhi(uy), 0.f);
    ((uint*)hb)[(size_t)n * 64 + lane] = packbf(h0, h1);
}

// ---------------------------------------------------------------------------
// Gather 2: out[n] = mean z2b[nbrs] + y2f[n]  (64-wide, fp32 out)
// 32-lane half-wave per node, 4-edge unroll.
// ---------------------------------------------------------------------------
__global__ __launch_bounds__(256) void k_gather2(const ushort* __restrict__ z2b,
                                                 const float* __restrict__ y2f,
                                                 const int* __restrict__ rowptr,
                                                 const int* __restrict__ col,
                                                 float* __restrict__ out)
{
    const int g = threadIdx.x >> 5, lane = threadIdx.x & 31;
    const int n = blockIdx.x * 8 + g;
    if (n >= NN) return;
    const int beg = rowptr[n], end = rowptr[n + 1];
    const uint* zu = (const uint*)z2b;
    float a0 = 0.f, a1 = 0.f;
    int e = beg;
    for (; e + 3 < end; e += 4) {
        int s0 = col[e], s1 = col[e + 1], s2 = col[e + 2], s3 = col[e + 3];
        uint u0 = zu[(size_t)s0 * 32 + lane];
        uint u1 = zu[(size_t)s1 * 32 + lane];
        uint u2 = zu[(size_t)s2 * 32 + lane];
        uint u3 = zu[(size_t)s3 * 32 + lane];
        a0 += bflo(u0) + bflo(u1) + bflo(u2) + bflo(u3);
        a1 += bfhi(u0) + bfhi(u1) + bfhi(u2) + bfhi(u3);
    }
    for (; e < end; ++e) {
        uint u0 = zu[(size_t)col[e] * 32 + lane];
        a0 += bflo(u0);
        a1 += bfhi(u0);
    }
    float inv = 1.0f / (float)max(end - beg, 1);
    float2 y = *reinterpret_cast<const float2*>(y2f + (size_t)n * 64 + lane * 2);
    float2 o;
    o.x = a0 * inv + y.x;
    o.y = a1 * inv + y.y;
    *reinterpret_cast<float2*>(out + (size_t)n * 64 + lane * 2) = o;
}

extern "C" void kernel_launch(void* const* d_in, const int* in_sizes, int n_in,
                              void* d_out, int out_size, void* d_ws, size_t ws_size,
                              hipStream_t stream)
{
    const float* x   = (const float*)d_in[0];
    const int*   ei  = (const int*)d_in[1];
    const float* W1l = (const float*)d_in[2];
    const float* W1r = (const float*)d_in[3];
    const float* b1  = (const float*)d_in[4];
    const float* W2l = (const float*)d_in[5];
    const float* W2r = (const float*)d_in[6];
    const float* b2  = (const float*)d_in[7];
    float* out = (float*)d_out;

    const int* src = ei;
    const int* dst = ei + NE;

    // workspace layout
    int*  rowptr = (int*)d_ws;                      // NN+1
    int*  pcnt   = rowptr + NN + 1;                 // 256
    int*  poff   = pcnt + 256;                      // 256 (NP+1 used)
    int*  gcur   = poff + 256;                      // 256
    uint* packed = (uint*)(gcur + 256);             // NE
    int*  colA   = (int*)(packed + NE);             // NE
    uintptr_t p = (uintptr_t)(colA + NE);
    p = (p + 255) & ~(uintptr_t)255;
    ushort* WbT1 = (ushort*)p;  p += (size_t)256 * 128 * 2;
    ushort* WbT2 = (ushort*)p;  p += (size_t)128 * 128 * 2;
    p = (p + 255) & ~(uintptr_t)255;
    ushort* z1b = (ushort*)p;   p += (size_t)NN * 128 * 2;  // row-major bf16
    ushort* y1b = (ushort*)p;   p += (size_t)NN * 128 * 2;  // row-major bf16
    ushort* hb  = (ushort*)p;   p += (size_t)NN * 128 * 2;  // row-major bf16
    ushort* z2b = z1b;                              // [NN][64] bf16, alias
    float*  y2f = (float*)y1b;                      // [NN][64] fp32, alias

    // ---- CSR build (partition-local) ----
    hipMemsetAsync(pcnt, 0, 256 * sizeof(int), stream);
    k_phist<<<NBIN, 256, 0, stream>>>(dst, pcnt);
    k_pscan<<<1, 256, 0, stream>>>(pcnt, poff, gcur, rowptr);
    k_binning<<<NBIN, 256, 0, stream>>>(src, dst, gcur, packed);
    k_pfill<<<NP, 256, 0, stream>>>(packed, poff, rowptr, colA);

    // ---- weights to bf16 (transposed) ----
    k_castw<<<(256 * 128 + 128 * 128 + 255) / 256, 256, 0, stream>>>(
        W1l, W1r, W2l, W2r, WbT1, WbT2);

    const int GM = (NN + 63) / 64;                  // 1563

    // ---- layer 1 ----
    k_gemmf<true><<<GM, 256, 0, stream>>>(x, WbT1, b1, z1b, y1b);
    k_gather1<<<(NN + 3) / 4, 256, 0, stream>>>(z1b, y1b, rowptr, colA, hb);

    // ---- layer 2 ----
    k_gemmf<false><<<GM, 256, 0, stream>>>(hb, WbT2, b2, z2b, y2f);
    k_gather2<<<(NN + 7) / 8, 256, 0, stream>>>(z2b, y2f, rowptr, colA, out);
}

// Round 7
// 276.582 us; speedup vs baseline: 2.1886x; 1.0155x over previous
//
#include <hip/hip_runtime.h>

#define NN 100000
#define NE 1600000
#define PSHIFT 9
#define PSZ 512
#define NP ((NN + PSZ - 1) / PSZ)             // 196
#define BCHUNK 8192
#define NBIN ((NE + BCHUNK - 1) / BCHUNK)     // 196
#define SRCMASK 0x1FFFF                       // 17 bits (NN < 131072)

typedef __attribute__((ext_vector_type(8))) short short8;
typedef __attribute__((ext_vector_type(4))) float f32x4;

__device__ __forceinline__ ushort f2bf(float f) {
    uint u = __float_as_uint(f);
    return (ushort)((u + 0x7FFFu + ((u >> 16) & 1u)) >> 16);   // RNE
}
__device__ __forceinline__ float bflo(uint u) { return __uint_as_float(u << 16); }
__device__ __forceinline__ float bfhi(uint u) { return __uint_as_float(u & 0xffff0000u); }
__device__ __forceinline__ uint packbf(float a, float b) {
    return (uint)f2bf(a) | ((uint)f2bf(b) << 16);
}

// ---------------------------------------------------------------------------
// CSR build, partition-local for write locality (round-4 proven).
// ---------------------------------------------------------------------------
__global__ __launch_bounds__(256) void k_phist(const int* __restrict__ dst,
                                               int* __restrict__ pcnt)
{
    __shared__ int cnt[256];
    const int tid = threadIdx.x;
    cnt[tid] = 0;
    __syncthreads();
    const long e0 = (long)blockIdx.x * BCHUNK;
    for (int i = tid; i < BCHUNK; i += 256) {
        long e = e0 + i;
        if (e < NE) atomicAdd(&cnt[dst[e] >> PSHIFT], 1);
    }
    __syncthreads();
    if (cnt[tid] > 0) atomicAdd(&pcnt[tid], cnt[tid]);
}

__global__ __launch_bounds__(256) void k_pscan(const int* __restrict__ pcnt,
                                               int* __restrict__ poff,
                                               int* __restrict__ gcur,
                                               int* __restrict__ rowptr)
{
    __shared__ int tmp[256];
    const int tid = threadIdx.x;
    int v = (tid < NP) ? pcnt[tid] : 0;
    tmp[tid] = v;
    __syncthreads();
    for (int off = 1; off < 256; off <<= 1) {
        int t = (tid >= off) ? tmp[tid - off] : 0;
        __syncthreads();
        tmp[tid] += t;
        __syncthreads();
    }
    int ex = tmp[tid] - v;
    if (tid < NP) { poff[tid] = ex; gcur[tid] = ex; }
    if (tid == 0) { poff[NP] = NE; rowptr[NN] = NE; }
}

__global__ __launch_bounds__(256) void k_binning(const int* __restrict__ src,
                                                 const int* __restrict__ dst,
                                                 int* __restrict__ gcur,
                                                 uint* __restrict__ packed)
{
    __shared__ int cnt[256];
    __shared__ int base[256];
    const int tid = threadIdx.x;
    const long e0 = (long)blockIdx.x * BCHUNK;
    cnt[tid] = 0;
    __syncthreads();
    for (int i = tid; i < BCHUNK; i += 256) {
        long e = e0 + i;
        if (e < NE) atomicAdd(&cnt[dst[e] >> PSHIFT], 1);
    }
    __syncthreads();
    if (cnt[tid] > 0) base[tid] = atomicAdd(&gcur[tid], cnt[tid]);
    cnt[tid] = 0;
    __syncthreads();
    for (int i = tid; i < BCHUNK; i += 256) {
        long e = e0 + i;
        if (e < NE) {
            int d = dst[e], s = src[e];
            int p = d >> PSHIFT;
            int ofs = atomicAdd(&cnt[p], 1);
            packed[base[p] + ofs] = (uint)s | ((uint)(d & (PSZ - 1)) << 17);
        }
    }
}

__global__ __launch_bounds__(256) void k_pfill(const uint* __restrict__ packed,
                                               const int* __restrict__ poff,
                                               int* __restrict__ rowptr,
                                               int* __restrict__ col)
{
    __shared__ int cnt[PSZ];
    __shared__ int cur[PSZ];
    __shared__ int tot[256];
    const int p   = blockIdx.x;
    const int tid = threadIdx.x;
    const int beg = poff[p], end = poff[p + 1];
    cnt[tid] = 0; cnt[tid + 256] = 0;
    __syncthreads();
    for (int i = beg + tid; i < end; i += 256)
        atomicAdd(&cnt[packed[i] >> 17], 1);
    __syncthreads();
    int v0 = cnt[tid * 2], v1 = cnt[tid * 2 + 1];
    int s  = v0 + v1;
    tot[tid] = s;
    __syncthreads();
    for (int off = 1; off < 256; off <<= 1) {
        int t = (tid >= off) ? tot[tid - off] : 0;
        __syncthreads();
        tot[tid] += t;
        __syncthreads();
    }
    int ex = tot[tid] - s + beg;
    cur[tid * 2]     = ex;
    cur[tid * 2 + 1] = ex + v0;
    int n0 = p * PSZ;
    if (n0 + tid * 2     < NN) rowptr[n0 + tid * 2]     = ex;
    if (n0 + tid * 2 + 1 < NN) rowptr[n0 + tid * 2 + 1] = ex + v0;
    __syncthreads();
    for (int i = beg + tid; i < end; i += 256) {
        uint v = packed[i];
        int pos = atomicAdd(&cur[v >> 17], 1);
        col[pos] = (int)(v & SRCMASK);
    }
}

// ---------------------------------------------------------------------------
// Weight prep: WbT1[256][128] = [W1_l | W1_r]^T bf16; WbT2[128][128]
// ---------------------------------------------------------------------------
__global__ __launch_bounds__(256) void k_castw(const float* __restrict__ W1l,
                                               const float* __restrict__ W1r,
                                               const float* __restrict__ W2l,
                                               const float* __restrict__ W2r,
                                               ushort* __restrict__ WbT1,
                                               ushort* __restrict__ WbT2)
{
    int i = blockIdx.x * 256 + threadIdx.x;
    if (i < 256 * 128) {
        int c = i >> 7, k = i & 127;
        float v = (c < 128) ? W1l[k * 128 + c] : W1r[k * 128 + (c - 128)];
        WbT1[i] = f2bf(v);
    } else if (i < 256 * 128 + 128 * 128) {
        int j = i - 256 * 128;
        int c = j >> 7, k = j & 127;
        float v = (c < 64) ? W2l[k * 64 + c] : W2r[k * 64 + (c - 64)];
        WbT2[j] = f2bf(v);
    }
}

// ---------------------------------------------------------------------------
// Fused dual-GEMM per layer: [z | y] = A @ [Wl | Wr] (+bias on y part).
// ---------------------------------------------------------------------------
template <bool IS_L1>
__global__ __launch_bounds__(256) void k_gemmf(const void* __restrict__ Ap,
                                               const ushort* __restrict__ Bt,
                                               const float* __restrict__ bias,
                                               ushort* __restrict__ zb,
                                               void* __restrict__ yout)
{
    constexpr int CB = IS_L1 ? 4 : 2;          // 16-col fragments per wave
    constexpr int ZW = IS_L1 ? 128 : 64;       // z width
    __shared__ ushort As[64 * 128];

    const int tid = threadIdx.x, bm = blockIdx.x;

    for (int c = tid; c < 1024; c += 256) {
        int row  = c >> 4;
        int coff = (c & 15) * 8;
        int gr   = bm * 64 + row;
        short8 va;
        if (gr < NN) {
            if (IS_L1) {
                const float* A = (const float*)Ap;
                float4 f0 = *reinterpret_cast<const float4*>(A + (size_t)gr * 128 + coff);
                float4 f1 = *reinterpret_cast<const float4*>(A + (size_t)gr * 128 + coff + 4);
                va[0] = (short)f2bf(f0.x); va[1] = (short)f2bf(f0.y);
                va[2] = (short)f2bf(f0.z); va[3] = (short)f2bf(f0.w);
                va[4] = (short)f2bf(f1.x); va[5] = (short)f2bf(f1.y);
                va[6] = (short)f2bf(f1.z); va[7] = (short)f2bf(f1.w);
            } else {
                const ushort* A = (const ushort*)Ap;
                va = *reinterpret_cast<const short8*>(A + (size_t)gr * 128 + coff);
            }
        } else {
            va = short8{0, 0, 0, 0, 0, 0, 0, 0};
        }
        int byte = row * 256 + coff * 2;
        byte ^= ((row & 7) << 4);
        *reinterpret_cast<short8*>(reinterpret_cast<char*>(As) + byte) = va;
    }
    __syncthreads();

    const int wid = tid >> 6, lane = tid & 63;
    const int lr  = lane & 15;
    const int lk  = (lane >> 4) << 3;

    f32x4 acc[4][CB];
#pragma unroll
    for (int mi = 0; mi < 4; ++mi)
#pragma unroll
        for (int nf = 0; nf < CB; ++nf) acc[mi][nf] = f32x4{0.f, 0.f, 0.f, 0.f};

    const char* pA = reinterpret_cast<const char*>(As);

#pragma unroll
    for (int ks = 0; ks < 4; ++ks) {
        int k2 = (ks * 32 + lk) * 2;
        short8 a[4], b[CB];
#pragma unroll
        for (int mi = 0; mi < 4; ++mi) {
            int r = mi * 16 + lr;
            int byte = r * 256 + k2;
            byte ^= ((r & 7) << 4);
            a[mi] = *reinterpret_cast<const short8*>(pA + byte);
        }
#pragma unroll
        for (int nf = 0; nf < CB; ++nf) {
            int colB = wid * (16 * CB) + nf * 16 + lr;
            b[nf] = *reinterpret_cast<const short8*>(Bt + (size_t)colB * 128 + ks * 32 + lk);
        }
#pragma unroll
        for (int mi = 0; mi < 4; ++mi)
#pragma unroll
            for (int nf = 0; nf < CB; ++nf)
                acc[mi][nf] = __builtin_amdgcn_mfma_f32_16x16x32_bf16(a[mi], b[nf], acc[mi][nf], 0, 0, 0);
    }

    // D mapping: col = lane&15, row = 4*(lane>>4) + reg
#pragma unroll
    for (int mi = 0; mi < 4; ++mi) {
#pragma unroll
        for (int nf = 0; nf < CB; ++nf) {
            int colg = wid * (16 * CB) + nf * 16 + lr;
#pragma unroll
            for (int rr = 0; rr < 4; ++rr) {
                int rowg = bm * 64 + mi * 16 + ((lane >> 4) << 2) + rr;
                if (rowg < NN) {
                    float v = acc[mi][nf][rr];
                    if (colg < ZW) {
                        zb[(size_t)rowg * ZW + colg] = f2bf(v);
                    } else {
                        int c2 = colg - ZW;
                        if (IS_L1) ((ushort*)yout)[(size_t)rowg * 128 + c2] = f2bf(v + bias[c2]);
                        else       ((float*)yout)[(size_t)rowg * 64 + c2]  = v + bias[c2];
                    }
                }
            }
        }
    }
}

// ---------------------------------------------------------------------------
// Gather 1: hb[n] = relu( mean z1b[nbrs] + y1b[n] )  (128-wide bf16)
// Wave per node; lanes split in halves: half = lane>>5 takes alternate edges,
// each lane loads uint2 (8B) -> one load round covers 2 edges; 8 edges per
// unrolled iteration. shfl_xor(32) merges halves.
// ---------------------------------------------------------------------------
__global__ __launch_bounds__(256) void k_gather1(const ushort* __restrict__ z1b,
                                                 const ushort* __restrict__ y1b,
                                                 const int* __restrict__ rowptr,
                                                 const int* __restrict__ col,
                                                 ushort* __restrict__ hb)
{
    const int w = threadIdx.x >> 6, lane = threadIdx.x & 63;
    const int n = blockIdx.x * 4 + w;
    if (n >= NN) return;
    const int half = lane >> 5, li = lane & 31;
    const int beg = rowptr[n], end = rowptr[n + 1];
    const uint2* zu = (const uint2*)z1b;      // row = 32 uint2
    float a0 = 0.f, a1 = 0.f, a2 = 0.f, a3 = 0.f;
    int e = beg;
    for (; e + 7 < end; e += 8) {
        int s0 = col[e     + half];
        int s1 = col[e + 2 + half];
        int s2 = col[e + 4 + half];
        int s3 = col[e + 6 + half];
        uint2 u0 = zu[(size_t)s0 * 32 + li];
        uint2 u1 = zu[(size_t)s1 * 32 + li];
        uint2 u2 = zu[(size_t)s2 * 32 + li];
        uint2 u3 = zu[(size_t)s3 * 32 + li];
        a0 += bflo(u0.x) + bflo(u1.x) + bflo(u2.x) + bflo(u3.x);
        a1 += bfhi(u0.x) + bfhi(u1.x) + bfhi(u2.x) + bfhi(u3.x);
        a2 += bflo(u0.y) + bflo(u1.y) + bflo(u2.y) + bflo(u3.y);
        a3 += bfhi(u0.y) + bfhi(u1.y) + bfhi(u2.y) + bfhi(u3.y);
    }
    for (; e + 1 < end; e += 2) {
        int s0 = col[e + half];
        uint2 u0 = zu[(size_t)s0 * 32 + li];
        a0 += bflo(u0.x); a1 += bfhi(u0.x);
        a2 += bflo(u0.y); a3 += bfhi(u0.y);
    }
    if (e < end && half == 0) {
        int s0 = col[e];
        uint2 u0 = zu[(size_t)s0 * 32 + li];
        a0 += bflo(u0.x); a1 += bfhi(u0.x);
        a2 += bflo(u0.y); a3 += bfhi(u0.y);
    }
    a0 += __shfl_xor(a0, 32); a1 += __shfl_xor(a1, 32);
    a2 += __shfl_xor(a2, 32); a3 += __shfl_xor(a3, 32);
    if (half == 0) {
        float inv = 1.0f / (float)max(end - beg, 1);
        uint2 uy = ((const uint2*)y1b)[(size_t)n * 32 + li];
        float h0 = fmaxf(a0 * inv + bflo(uy.x), 0.f);
        float h1 = fmaxf(a1 * inv + bfhi(uy.x), 0.f);
        float h2 = fmaxf(a2 * inv + bflo(uy.y), 0.f);
        float h3 = fmaxf(a3 * inv + bfhi(uy.y), 0.f);
        uint2 o;
        o.x = packbf(h0, h1);
        o.y = packbf(h2, h3);
        ((uint2*)hb)[(size_t)n * 32 + li] = o;
    }
}

// ---------------------------------------------------------------------------
// Gather 2: out[n] = mean z2b[nbrs] + y2f[n]  (64-wide, fp32 out)
// Wave per node; quarters: quar = lane>>4 takes every 4th edge, uint2 loads
// -> one load round covers 4 edges; 16 edges per unrolled iteration.
// shfl_xor(16|32) merges quarters.
// ---------------------------------------------------------------------------
__global__ __launch_bounds__(256) void k_gather2(const ushort* __restrict__ z2b,
                                                 const float* __restrict__ y2f,
                                                 const int* __restrict__ rowptr,
                                                 const int* __restrict__ col,
                                                 float* __restrict__ out)
{
    const int w = threadIdx.x >> 6, lane = threadIdx.x & 63;
    const int n = blockIdx.x * 4 + w;
    if (n >= NN) return;
    const int quar = lane >> 4, li = lane & 15;
    const int beg = rowptr[n], end = rowptr[n + 1];
    const uint2* zu = (const uint2*)z2b;      // row = 16 uint2
    float a0 = 0.f, a1 = 0.f, a2 = 0.f, a3 = 0.f;
    int e = beg;
    for (; e + 15 < end; e += 16) {
        int s0 = col[e      + quar];
        int s1 = col[e + 4  + quar];
        int s2 = col[e + 8  + quar];
        int s3 = col[e + 12 + quar];
        uint2 u0 = zu[(size_t)s0 * 16 + li];
        uint2 u1 = zu[(size_t)s1 * 16 + li];
        uint2 u2 = zu[(size_t)s2 * 16 + li];
        uint2 u3 = zu[(size_t)s3 * 16 + li];
        a0 += bflo(u0.x) + bflo(u1.x) + bflo(u2.x) + bflo(u3.x);
        a1 += bfhi(u0.x) + bfhi(u1.x) + bfhi(u2.x) + bfhi(u3.x);
        a2 += bflo(u0.y) + bflo(u1.y) + bflo(u2.y) + bflo(u3.y);
        a3 += bfhi(u0.y) + bfhi(u1.y) + bfhi(u2.y) + bfhi(u3.y);
    }
    for (; e + 3 < end; e += 4) {
        int s0 = col[e + quar];
        uint2 u0 = zu[(size_t)s0 * 16 + li];
        a0 += bflo(u0.x); a1 += bfhi(u0.x);
        a2 += bflo(u0.y); a3 += bfhi(u0.y);
    }
    int rem = end - e;
    if (quar < rem) {
        int s0 = col[e + quar];
        uint2 u0 = zu[(size_t)s0 * 16 + li];
        a0 += bflo(u0.x); a1 += bfhi(u0.x);
        a2 += bflo(u0.y); a3 += bfhi(u0.y);
    }
    a0 += __shfl_xor(a0, 16); a1 += __shfl_xor(a1, 16);
    a2 += __shfl_xor(a2, 16); a3 += __shfl_xor(a3, 16);
    a0 += __shfl_xor(a0, 32); a1 += __shfl_xor(a1, 32);
    a2 += __shfl_xor(a2, 32); a3 += __shfl_xor(a3, 32);
    if (quar == 0) {
        float inv = 1.0f / (float)max(end - beg, 1);
        float4 y = ((const float4*)y2f)[(size_t)n * 16 + li];
        float4 o;
        o.x = a0 * inv + y.x;
        o.y = a1 * inv + y.y;
        o.z = a2 * inv + y.z;
        o.w = a3 * inv + y.w;
        ((float4*)out)[(size_t)n * 16 + li] = o;
    }
}

extern "C" void kernel_launch(void* const* d_in, const int* in_sizes, int n_in,
                              void* d_out, int out_size, void* d_ws, size_t ws_size,
                              hipStream_t stream)
{
    const float* x   = (const float*)d_in[0];
    const int*   ei  = (const int*)d_in[1];
    const float* W1l = (const float*)d_in[2];
    const float* W1r = (const float*)d_in[3];
    const float* b1  = (const float*)d_in[4];
    const float* W2l = (const float*)d_in[5];
    const float* W2r = (const float*)d_in[6];
    const float* b2  = (const float*)d_in[7];
    float* out = (float*)d_out;

    const int* src = ei;
    const int* dst = ei + NE;

    // workspace layout
    int*  rowptr = (int*)d_ws;                      // NN+1
    int*  pcnt   = rowptr + NN + 1;                 // 256
    int*  poff   = pcnt + 256;                      // 256 (NP+1 used)
    int*  gcur   = poff + 256;                      // 256
    uint* packed = (uint*)(gcur + 256);             // NE
    int*  colA   = (int*)(packed + NE);             // NE
    uintptr_t p = (uintptr_t)(colA + NE);
    p = (p + 255) & ~(uintptr_t)255;
    ushort* WbT1 = (ushort*)p;  p += (size_t)256 * 128 * 2;
    ushort* WbT2 = (ushort*)p;  p += (size_t)128 * 128 * 2;
    p = (p + 255) & ~(uintptr_t)255;
    ushort* z1b = (ushort*)p;   p += (size_t)NN * 128 * 2;  // row-major bf16
    ushort* y1b = (ushort*)p;   p += (size_t)NN * 128 * 2;  // row-major bf16
    ushort* hb  = (ushort*)p;   p += (size_t)NN * 128 * 2;  // row-major bf16
    ushort* z2b = z1b;                              // [NN][64] bf16, alias
    float*  y2f = (float*)y1b;                      // [NN][64] fp32, alias

    // ---- CSR build (partition-local) ----
    hipMemsetAsync(pcnt, 0, 256 * sizeof(int), stream);
    k_phist<<<NBIN, 256, 0, stream>>>(dst, pcnt);
    k_pscan<<<1, 256, 0, stream>>>(pcnt, poff, gcur, rowptr);
    k_binning<<<NBIN, 256, 0, stream>>>(src, dst, gcur, packed);
    k_pfill<<<NP, 256, 0, stream>>>(packed, poff, rowptr, colA);

    // ---- weights to bf16 (transposed) ----
    k_castw<<<(256 * 128 + 128 * 128 + 255) / 256, 256, 0, stream>>>(
        W1l, W1r, W2l, W2r, WbT1, WbT2);

    const int GM = (NN + 63) / 64;                  // 1563

    // ---- layer 1 ----
    k_gemmf<true><<<GM, 256, 0, stream>>>(x, WbT1, b1, z1b, y1b);
    k_gather1<<<(NN + 3) / 4, 256, 0, stream>>>(z1b, y1b, rowptr, colA, hb);

    // ---- layer 2 ----
    k_gemmf<false><<<GM, 256, 0, stream>>>(hb, WbT2, b2, z2b, y2f);
    k_gather2<<<(NN + 3) / 4, 256, 0, stream>>>(z2b, y2f, rowptr, colA, out);
}